// Round 4
// baseline (365.843 us; speedup 1.0000x reference)
//
#include <hip/hip_runtime.h>
#include <hip/hip_bf16.h>
#include <stdint.h>

#define B_ 4
#define S_ 2048
#define D_ 1024
#define M_ 4

typedef __bf16 bf16;
typedef _Float16 f16;
typedef unsigned char u8;
typedef __bf16 bf16x8 __attribute__((ext_vector_type(8)));
typedef _Float16 f16x8 __attribute__((ext_vector_type(8)));
typedef float f32x4 __attribute__((ext_vector_type(4)));

__device__ __forceinline__ void async_copy16(const void* g, void* l) {
  __builtin_amdgcn_global_load_lds(
      (const __attribute__((address_space(1))) void*)g,
      (__attribute__((address_space(3))) void*)l, 16, 0, 0);
}

// Fused prep, block ranges:
//   [0,4096)      : x fp32 -> bf16
//   [4096,5120)   : 4x W [1024,1024] fp32 -> WT bf16 (256 blocks each)
//   [5120,7168)   : pack 4 masks -> bitfield bytes
__global__ __launch_bounds__(256) void prep(
    const float* __restrict__ x, const float* __restrict__ w0,
    const float* __restrict__ w1, const float* __restrict__ w2,
    const float* __restrict__ w3, const int* __restrict__ masks,
    bf16* __restrict__ xc, bf16* __restrict__ WT, u8* __restrict__ pk) {
  __shared__ bf16 t[64][65];
  const int blk = blockIdx.x;
  const int tid = threadIdx.x;
  const long SS = (long)S_ * S_;

  if (blk < 4096) {  // x -> bf16
    const long i = (long)blk * 2048 + tid * 8;
    const float4 a = *(const float4*)(x + i);
    const float4 b = *(const float4*)(x + i + 4);
    bf16x8 o;
    o[0] = (bf16)a.x; o[1] = (bf16)a.y; o[2] = (bf16)a.z; o[3] = (bf16)a.w;
    o[4] = (bf16)b.x; o[5] = (bf16)b.y; o[6] = (bf16)b.z; o[7] = (bf16)b.w;
    *(bf16x8*)(xc + i) = o;
  } else if (blk < 5120) {  // weight transpose -> bf16
    const int local = blk - 4096;
    const int z = local >> 8;
    const int rem = local & 255;
    const int r0 = (rem >> 4) * 64;
    const int c0 = (rem & 15) * 64;
    const int tx = tid & 63;
    const int ty = tid >> 6;
    const float* in = (z == 0) ? w0 : (z == 1) ? w1 : (z == 2) ? w2 : w3;
    bf16* out = WT + (long)z * D_ * D_;
    for (int i = ty; i < 64; i += 4)
      t[i][tx] = (bf16)in[(long)(r0 + i) * D_ + c0 + tx];
    __syncthreads();
    for (int i = ty; i < 64; i += 4)
      out[(long)(c0 + i) * D_ + r0 + tx] = t[tx][i];
  } else {  // pack masks
    const long e = (long)(blk - 5120) * 2048 + tid * 8;
    unsigned long long wv = 0;
#pragma unroll
    for (int m = 0; m < M_; ++m) {
      const int4 a = *(const int4*)(masks + m * SS + e);
      const int4 b = *(const int4*)(masks + m * SS + e + 4);
      const int v[8] = {a.x, a.y, a.z, a.w, b.x, b.y, b.z, b.w};
#pragma unroll
      for (int j = 0; j < 8; ++j)
        wv |= (unsigned long long)(v[j] != 0 ? 1u : 0u) << (8 * j + m);
    }
    *(unsigned long long*)(pk + e) = wv;
  }
}

// batched bf16 [rows,cols] -> [cols,rows] transpose (z = batch)
__global__ __launch_bounds__(256) void transposeB(
    const bf16* __restrict__ in, bf16* __restrict__ out,
    int rows, int cols, long ib, long ob) {
  __shared__ bf16 t[64][65];
  in += (long)blockIdx.z * ib;
  out += (long)blockIdx.z * ob;
  const int r0 = blockIdx.y * 64;
  const int c0 = blockIdx.x * 64;
  const int tx = threadIdx.x & 63;
  const int ty = threadIdx.x >> 6;
#pragma unroll
  for (int i = ty; i < 64; i += 4) t[i][tx] = in[(long)(r0 + i) * cols + c0 + tx];
  __syncthreads();
#pragma unroll
  for (int i = ty; i < 64; i += 4) out[(long)(c0 + i) * rows + r0 + tx] = t[tx][i];
}

#define MODE_PLAIN 0
#define MODE_EXP 1   // C = exp(alpha*acc), f16 out; B z-batched by row0>>11
#define MODE_QKV 2   // N=3072 grouped epilogue: Q | K | V
#define MODE_PV 3    // B z-batched by row0>>11

// ---------------- 256x128 register-ping-pong counted-vmcnt GEMM ----------------
// 512 threads = 8 waves (4M x 2N), per-wave output 64x64 (acc 4x4).
// LDS: As[2][2][256*32] 64K + Bs[2][2][128*32] 32K = 96 KiB, 1 block/CU.
// K split into halves h (32 cols each); slot(h) = ((h>>1)&1, h&1).
// Register ping-pong: fragments for half h+1 are ds_read DURING half h's MFMA
// cluster (MFMA(h) depends only on regs loaded one phase earlier), so the LDS
// pipe (~768 cyc for 64 ds_read_b128/CU) overlaps the MFMA pipe (~621 cyc)
// instead of serializing (round-3 failure: 1889 cyc/phase at 28% MfmaUtil).
// Phase h (steady state):
//   vmcnt(3) [publish half h+1: retires its 3 loads, leaves next stage in
//   flight] | s_barrier | sched_barrier | ds_read frags(h+1) -> other reg set
//   | STAGE(half h+3) | MFMA(regs of h)
// vmcnt ledger (3 loads/stage: A x2 + B x1, per thread): stage(h+3) issued in
// phase h; publish(h+1) at top of phase h -> outstanding before vmcnt = halves
// {h+1, h+2} = 6, retire 3 -> vmcnt(3). Final publish (h = 2nk-1 at top of
// t = nk-1 even phase) -> vmcnt(0). WAR: stage(h+3) overwrites slot of half
// h-1, whose reads were lgkm-complete before MFMA(h-1), which precedes the
// barrier at top of phase h -> safe. Cross-wave RAW: per-wave vmcnt sits
// BEFORE s_barrier, so barrier-exit implies all waves' DMA for that half
// retired. sched_barrier(0) pins reads/stages below the barrier.
// Swizzle (validated r1-r3): 16B slot stored at slot^((row>>1)&3) via
// pre-swizzled GLOBAL source + linear LDS dest + swizzled ds_read.
// Requires nk >= 2 (all uses have nk >= 16).
template <typename OutT, int MODE>
__global__ __launch_bounds__(512) void gemmA(
    const bf16* __restrict__ A, int lda,
    const bf16* __restrict__ Bt, long bzs, int ldb,
    OutT* __restrict__ C, int ldc,
    const float* __restrict__ bias0, const float* __restrict__ bias1,
    const float* __restrict__ bias2, float alpha, int K) {
  __shared__ __align__(16) bf16 As[2][2][256 * 32];
  __shared__ __align__(16) bf16 Bs[2][2][128 * 32];
  const int tid = threadIdx.x;
  const int lane = tid & 63;
  const int w = tid >> 6;
  const int wm = w & 3;   // wave-row: rows wm*64..+64
  const int wn = w >> 2;  // wave-col: cols wn*64..+64
  const int quad = lane >> 4;
  const int l15 = lane & 15;
  // swizzled frag slot: (row>>1)&3 == (l15>>1)&3 for all frag rows -> lane-const
  const int fse = (quad ^ ((l15 >> 1) & 3)) << 3;

  // GROUP-8 M-swizzle for XCD/L2 locality (gridDim.y = 32 in all launches)
  const int gx = gridDim.x;
  const int pid = blockIdx.y * gx + blockIdx.x;
  const int gsz = 8 * gx;
  const int bym = (pid / gsz) * 8 + (pid % 8);
  const int bxm = (pid % gsz) / 8;
  const int row0 = bym * 256;
  const int col0 = bxm * 128;

  const bf16* Arow = A + (long)row0 * lda;
  const bf16* Bcol;
  int grp = 0;
  if (MODE == MODE_QKV) {
    grp = col0 >> 10;  // 128-col tile never straddles a 1024 group boundary
    Bcol = Bt + (long)grp * ((long)D_ * D_) + (long)(col0 & (D_ - 1)) * ldb;
  } else if (MODE == MODE_PV || MODE == MODE_EXP) {
    Bcol = Bt + (long)(row0 >> 11) * bzs + (long)col0 * ldb;
  } else {
    Bcol = Bt + (long)col0 * ldb;
  }

  // per-thread staging constants (pre-swizzled global source)
  const int sr = tid >> 2;                            // row 0..127
  const int sc = ((tid & 3) ^ ((tid >> 3) & 3)) << 3; // swizzled 16B slot
  const bf16* gA = Arow + (long)sr * lda + sc;
  const bf16* gB = Bcol + (long)sr * ldb + sc;
  const int dstoff = (tid >> 6) << 9;  // wave-uniform base (elems)
  const long a128 = (long)128 * lda;

#define STAGE(h)                                                       \
  {                                                                    \
    const int kc_ = (h) * 32;                                          \
    bf16* da_ = &As[((h) >> 1) & 1][(h) & 1][0] + dstoff;              \
    bf16* db_ = &Bs[((h) >> 1) & 1][(h) & 1][0] + dstoff;              \
    async_copy16(gA + kc_, da_);                                       \
    async_copy16(gA + kc_ + a128, da_ + 4096);                         \
    async_copy16(gB + kc_, db_);                                       \
  }

#define READF(Ra, Rb, bufv, ksv)                                           \
  {                                                                        \
    const bf16* pa_ = &As[bufv][ksv][0];                                   \
    const bf16* pb_ = &Bs[bufv][ksv][0];                                   \
    _Pragma("unroll") for (int j = 0; j < 4; ++j) {                        \
      Ra[j] = *(const bf16x8*)&pa_[(wm * 64 + j * 16 + l15) * 32 + fse];   \
      Rb[j] = *(const bf16x8*)&pb_[(wn * 64 + j * 16 + l15) * 32 + fse];   \
    }                                                                      \
  }

#define MM(Ra, Rb)                                                         \
  __builtin_amdgcn_s_setprio(1);                                           \
  _Pragma("unroll") for (int mi = 0; mi < 4; ++mi)                         \
      _Pragma("unroll") for (int ni = 0; ni < 4; ++ni) acc[mi][ni] =       \
          __builtin_amdgcn_mfma_f32_16x16x32_bf16(Ra[mi], Rb[ni],          \
                                                  acc[mi][ni], 0, 0, 0);   \
  __builtin_amdgcn_s_setprio(0);

  f32x4 acc[4][4];
#pragma unroll
  for (int i = 0; i < 4; ++i)
#pragma unroll
    for (int j = 0; j < 4; ++j) acc[i][j] = (f32x4){0.f, 0.f, 0.f, 0.f};

  const int nk = K >> 6;

  // prologue: stage halves 0,1,2; publish half 0 (vmcnt(6)); read its frags.
  STAGE(0);
  STAGE(1);
  STAGE(2);
  asm volatile("s_waitcnt vmcnt(6)" ::: "memory");
  __builtin_amdgcn_s_barrier();
  __builtin_amdgcn_sched_barrier(0);

  bf16x8 a0[4], b0[4], a1[4], b1[4];
  READF(a0, b0, 0, 0);

  for (int t = 0; t < nk; ++t) {
    const int buf = t & 1;

    // ---- phase even: half 2t (regs a0/b0); publish half 2t+1 ----
    if (t + 1 < nk)
      asm volatile("s_waitcnt vmcnt(3)" ::: "memory");
    else
      asm volatile("s_waitcnt vmcnt(0)" ::: "memory");
    __builtin_amdgcn_s_barrier();
    __builtin_amdgcn_sched_barrier(0);
    READF(a1, b1, buf, 1);           // frags for half 2t+1
    if (t + 1 < nk) STAGE(2 * t + 3);
    MM(a0, b0);

    // ---- phase odd: half 2t+1 (regs a1/b1); publish half 2t+2 ----
    if (t + 1 < nk) {
      asm volatile("s_waitcnt vmcnt(3)" ::: "memory");
      __builtin_amdgcn_s_barrier();
      __builtin_amdgcn_sched_barrier(0);
      READF(a0, b0, buf ^ 1, 0);     // frags for half 2t+2
      if (t + 3 <= nk) STAGE(2 * t + 4);
    }
    MM(a1, b1);
  }

#undef STAGE
#undef READF
#undef MM

  // epilogue: C/D layout col = lane&15, row = quad*4 + reg
  const float* bias = (MODE == MODE_QKV)
                          ? (grp == 0 ? bias0 : grp == 1 ? bias1 : bias2)
                          : bias0;
  const long NX = (long)B_ * S_ * D_;
  OutT* Cb = (MODE == MODE_QKV) ? C + (long)grp * NX : C;
#pragma unroll
  for (int mi = 0; mi < 4; ++mi)
#pragma unroll
    for (int ni = 0; ni < 4; ++ni) {
      const int col = col0 + wn * 64 + ni * 16 + l15;
      const int ccol = (MODE == MODE_QKV) ? (col & (D_ - 1)) : col;
      const float bv = bias ? bias[ccol] : 0.0f;
#pragma unroll
      for (int r = 0; r < 4; ++r) {
        const int row = row0 + wm * 64 + mi * 16 + quad * 4 + r;
        const float val = acc[mi][ni][r] * alpha + bv;
        if (MODE == MODE_EXP) {
          Cb[(long)row * ldc + col] = (OutT)__expf(val);
        } else if (MODE == MODE_QKV) {
          Cb[(long)row * D_ + ccol] = (OutT)val;
        } else {
          Cb[(long)row * ldc + col] = (OutT)val;
        }
      }
    }
}

// grid (S, B): P[b,q,:] = E[b,q,:] * sum_m bit_m(q,:) / rowsum_m / M, bf16.
__global__ __launch_bounds__(256) void softmax_combine(
    const f16* __restrict__ E, const u8* __restrict__ pk, bf16* __restrict__ P) {
  const int q = blockIdx.x;
  const int b = blockIdx.y;
  const int tid = threadIdx.x;
  const int lane = tid & 63;
  const int wv = tid >> 6;
  __shared__ float4 red[4];

  float e[8];
  {
    const f16x8 h = *(const f16x8*)(E + ((long)b * S_ + q) * S_ + tid * 8);
#pragma unroll
    for (int j = 0; j < 8; ++j) e[j] = (float)h[j];
  }
  const unsigned long long mb =
      *(const unsigned long long*)(pk + (long)q * S_ + tid * 8);

  float4 s = {0.f, 0.f, 0.f, 0.f};
#pragma unroll
  for (int j = 0; j < 8; ++j) {
    const unsigned bits = (unsigned)(mb >> (8 * j)) & 0xF;
    const float ev = e[j];
    if (bits & 1) s.x += ev;
    if (bits & 2) s.y += ev;
    if (bits & 4) s.z += ev;
    if (bits & 8) s.w += ev;
  }
#pragma unroll
  for (int o = 32; o > 0; o >>= 1) {
    s.x += __shfl_xor(s.x, o, 64);
    s.y += __shfl_xor(s.y, o, 64);
    s.z += __shfl_xor(s.z, o, 64);
    s.w += __shfl_xor(s.w, o, 64);
  }
  if (lane == 0) red[wv] = s;
  __syncthreads();
  const float4 t0 = red[0], t1 = red[1], t2 = red[2], t3 = red[3];
  const float r0 = 0.25f / (t0.x + t1.x + t2.x + t3.x);
  const float r1 = 0.25f / (t0.y + t1.y + t2.y + t3.y);
  const float r2 = 0.25f / (t0.z + t1.z + t2.z + t3.z);
  const float r3 = 0.25f / (t0.w + t1.w + t2.w + t3.w);

  bf16x8 o;
#pragma unroll
  for (int j = 0; j < 8; ++j) {
    const unsigned bits = (unsigned)(mb >> (8 * j)) & 0xF;
    const float wgt = ((bits & 1) ? r0 : 0.f) + ((bits & 2) ? r1 : 0.f) +
                      ((bits & 4) ? r2 : 0.f) + ((bits & 8) ? r3 : 0.f);
    o[j] = (bf16)(e[j] * wgt);
  }
  *(bf16x8*)(P + ((long)b * S_ + q) * S_ + tid * 8) = o;
}

extern "C" void kernel_launch(void* const* d_in, const int* in_sizes, int n_in,
                              void* d_out, int out_size, void* d_ws, size_t ws_size,
                              hipStream_t stream) {
  const float* x = (const float*)d_in[0];
  const int* masks = (const int*)d_in[1];
  const float* bq = (const float*)d_in[3];
  const float* bk = (const float*)d_in[5];
  const float* bv = (const float*)d_in[7];
  const float* bo = (const float*)d_in[9];
  float* out = (float*)d_out;

  const long DD = (long)D_ * D_;
  const long SD = (long)S_ * D_;
  const long NX = (long)B_ * SD;
  const long SS = (long)S_ * S_;

  // ws: xc 16M | WT 8M | pk 4M | Q/K/V 48M | VT 16M | P 32M | E 32M = 156 MiB
  bf16* xc = (bf16*)d_ws;
  bf16* WqT = xc + NX;  // WkT, WvT, WoT contiguous after
  bf16* WoT = WqT + 3 * DD;
  u8* pk = (u8*)(WoT + DD);    // [S][S] mask bitfield
  bf16* Q = (bf16*)(pk + SS);  // K = Q+NX, V = K+NX (QKV epilogue relies on it)
  bf16* K = Q + NX;
  bf16* V = K + NX;
  bf16* VT = V + NX;
  bf16* P = VT + NX;                   // [B][S][S] bf16
  f16* E = (f16*)(P + (long)B_ * SS);  // [B][S][S] f16
  bf16* attn = Q;                      // attn overwrites dead Q

  dim3 blk(256);
  dim3 blk512(512);

  // fused prep: x->bf16, 4 weight transposes, mask pack (one launch)
  prep<<<dim3(7168), blk, 0, stream>>>(
      x, (const float*)d_in[2], (const float*)d_in[4], (const float*)d_in[6],
      (const float*)d_in[8], masks, xc, WqT, pk);

  // fused Q|K|V projection: [8192,1024] x [1024,3072], 256x128 tiles
  // grid 24x32 = 768 blocks = 3 exact rounds
  gemmA<bf16, MODE_QKV><<<dim3(24, 32), blk512, 0, stream>>>(
      xc, D_, WqT, 0, D_, Q, D_, bq, bk, bv, 1.0f, D_);

  // VT[b][d][s] = V[b][s][d]
  transposeB<<<dim3(16, 32, B_), blk, 0, stream>>>(V, VT, S_, D_, SD, SD);

  // E = exp(Q K^T / 32) : flat [8192,1024] x K[z][2048,1024], z = row>>11
  // grid 16x32 = 512 blocks = 2 exact rounds; E flat [8192][2048] == [B][S][S]
  gemmA<f16, MODE_EXP><<<dim3(16, 32), blk512, 0, stream>>>(
      Q, D_, K, SD, D_, E, S_, nullptr, nullptr, nullptr, 1.0f / 32.0f, D_);

  // P = E * sum_m mask_m / rowsum_m / M
  softmax_combine<<<dim3(S_, B_), blk, 0, stream>>>(E, pk, P);

  // attn = P @ V : flat [8192,2048] x VT[z][1024,2048], K=2048
  // grid 8x32 = 256 blocks = 1 exact round
  gemmA<bf16, MODE_PV><<<dim3(8, 32), blk512, 0, stream>>>(
      P, S_, VT, SD, S_, attn, D_, nullptr, nullptr, nullptr, 1.0f, S_);

  // out = attn @ Wo + bo : fp32 epilogue straight to d_out (256 blocks = 1 round)
  gemmA<float, MODE_PLAIN><<<dim3(8, 32), blk512, 0, stream>>>(
      attn, D_, WoT, 0, D_, out, D_, bo, nullptr, nullptr, 1.0f, D_);
}

// Round 7
// 361.015 us; speedup vs baseline: 1.0134x; 1.0134x over previous
//
#include <hip/hip_runtime.h>
#include <hip/hip_bf16.h>
#include <stdint.h>

#define B_ 4
#define S_ 2048
#define D_ 1024
#define M_ 4

typedef __bf16 bf16;
typedef _Float16 f16;
typedef unsigned char u8;
typedef __bf16 bf16x8 __attribute__((ext_vector_type(8)));
typedef _Float16 f16x8 __attribute__((ext_vector_type(8)));
typedef float f32x4 __attribute__((ext_vector_type(4)));

__device__ __forceinline__ void async_copy16(const void* g, void* l) {
  __builtin_amdgcn_global_load_lds(
      (const __attribute__((address_space(1))) void*)g,
      (__attribute__((address_space(3))) void*)l, 16, 0, 0);
}

// Fused prep, block ranges:
//   [0,4096)      : x fp32 -> bf16
//   [4096,5120)   : 4x W [1024,1024] fp32 -> WT bf16 (256 blocks each)
//   [5120,7168)   : pack 4 masks -> bitfield bytes
__global__ __launch_bounds__(256) void prep(
    const float* __restrict__ x, const float* __restrict__ w0,
    const float* __restrict__ w1, const float* __restrict__ w2,
    const float* __restrict__ w3, const int* __restrict__ masks,
    bf16* __restrict__ xc, bf16* __restrict__ WT, u8* __restrict__ pk) {
  __shared__ bf16 t[64][65];
  const int blk = blockIdx.x;
  const int tid = threadIdx.x;
  const long SS = (long)S_ * S_;

  if (blk < 4096) {  // x -> bf16
    const long i = (long)blk * 2048 + tid * 8;
    const float4 a = *(const float4*)(x + i);
    const float4 b = *(const float4*)(x + i + 4);
    bf16x8 o;
    o[0] = (bf16)a.x; o[1] = (bf16)a.y; o[2] = (bf16)a.z; o[3] = (bf16)a.w;
    o[4] = (bf16)b.x; o[5] = (bf16)b.y; o[6] = (bf16)b.z; o[7] = (bf16)b.w;
    *(bf16x8*)(xc + i) = o;
  } else if (blk < 5120) {  // weight transpose -> bf16
    const int local = blk - 4096;
    const int z = local >> 8;
    const int rem = local & 255;
    const int r0 = (rem >> 4) * 64;
    const int c0 = (rem & 15) * 64;
    const int tx = tid & 63;
    const int ty = tid >> 6;
    const float* in = (z == 0) ? w0 : (z == 1) ? w1 : (z == 2) ? w2 : w3;
    bf16* out = WT + (long)z * D_ * D_;
    for (int i = ty; i < 64; i += 4)
      t[i][tx] = (bf16)in[(long)(r0 + i) * D_ + c0 + tx];
    __syncthreads();
    for (int i = ty; i < 64; i += 4)
      out[(long)(c0 + i) * D_ + r0 + tx] = t[tx][i];
  } else {  // pack masks
    const long e = (long)(blk - 5120) * 2048 + tid * 8;
    unsigned long long wv = 0;
#pragma unroll
    for (int m = 0; m < M_; ++m) {
      const int4 a = *(const int4*)(masks + m * SS + e);
      const int4 b = *(const int4*)(masks + m * SS + e + 4);
      const int v[8] = {a.x, a.y, a.z, a.w, b.x, b.y, b.z, b.w};
#pragma unroll
      for (int j = 0; j < 8; ++j)
        wv |= (unsigned long long)(v[j] != 0 ? 1u : 0u) << (8 * j + m);
    }
    *(unsigned long long*)(pk + e) = wv;
  }
}

// batched bf16 [rows,cols] -> [cols,rows] transpose (z = batch)
__global__ __launch_bounds__(256) void transposeB(
    const bf16* __restrict__ in, bf16* __restrict__ out,
    int rows, int cols, long ib, long ob) {
  __shared__ bf16 t[64][65];
  in += (long)blockIdx.z * ib;
  out += (long)blockIdx.z * ob;
  const int r0 = blockIdx.y * 64;
  const int c0 = blockIdx.x * 64;
  const int tx = threadIdx.x & 63;
  const int ty = threadIdx.x >> 6;
#pragma unroll
  for (int i = ty; i < 64; i += 4) t[i][tx] = in[(long)(r0 + i) * cols + c0 + tx];
  __syncthreads();
#pragma unroll
  for (int i = ty; i < 64; i += 4) out[(long)(c0 + i) * rows + r0 + tx] = t[tx][i];
}

#define MODE_PLAIN 0
#define MODE_EXP 1   // C = exp(alpha*acc), f16 out (scores -> E)
#define MODE_QKV 2   // N=3072 grouped epilogue: Q | K | V
#define MODE_PV 3    // z-batched B operand: z = row0>>11 (8 row-blocks per batch)

// Staging: 16B slot stored at slot^((row>>1)&3) via pre-swizzled GLOBAL source +
// linear LDS dest (global_load_lds constraint) + swizzled ds_read -> conflict-free.
// stage128: 128 rows x 32 cols (8 KB), 1 load/thread.
__device__ __forceinline__ void stage128(const bf16* __restrict__ G, int ld,
                                         int kcol, bf16* region, int tid) {
  const int r = tid >> 2;
  const int c = ((tid & 3) ^ ((tid >> 3) & 3)) << 3;  // pre-swizzled col (elems)
  async_copy16(G + (long)r * ld + kcol + c, region + ((tid >> 6) << 9));
}
// stage256: 256 rows x 32 cols (16 KB), 2 loads/thread (rows 128.. share swizzle bits)
__device__ __forceinline__ void stage256(const bf16* __restrict__ G, int ld,
                                         int kcol, bf16* region, int tid) {
  const int r = tid >> 2;
  const int c = ((tid & 3) ^ ((tid >> 3) & 3)) << 3;
  const bf16* g = G + (long)r * ld + kcol + c;
  bf16* dst = region + ((tid >> 6) << 9);  // wave-uniform base, HW adds lane*16B
  async_copy16(g, dst);
  async_copy16(g + (long)128 * ld, dst + 4096);
}

// ---------------- 256x128 2-phase balanced counted-vmcnt GEMM ----------------
// 512 threads = 8 waves (4M x 2N), per-wave output 64x64 (acc 4x4).
// LDS: As[2][2][256*32] 64K + Bs[2][2][128*32] 32K = 96 KiB.
// Per K-tile (BK=64, split kh0/kh1): 2 phases (ks=0,1). Each phase:
//   {8 ds_read_b128 (4 A + 4 B frags) | stage next half-tile (A:2 + B:1 loads)
//    | 16 MFMA | vmcnt(6) | s_barrier | sched_barrier}
// vmcnt ledger (3 loads per half-tile-stage, per thread):
//   P1(t) stages kh1(t+1)->buf^1; end-P1 in-flight [kh1(t),kh0(t+1),kh1(t+1)]=9,
//   vmcnt(6) retires kh1(t) (needed by P2(t)).
//   P2(t) stages kh0(t+2)->buf;   end-P2 in-flight [kh0(t+1),kh1(t+1),kh0(t+2)]=9,
//   vmcnt(6) retires kh0(t+1) (needed by P1(t+1)).
//   Tail: t=nk-2 P2 -> vmcnt(3); t=nk-1 P1 -> vmcnt(0); P2(nk-1) none in flight.
// WAR: each stage targets a region whose readers finished >=1 barrier earlier
// (kh1 of buf^1 last read P2(t-1); kh0 of buf last read P1(t)); sched_barrier(0)
// after each s_barrier pins stages/reads below the barrier.
// vmcnt sits AFTER the MFMA cluster so MFMAs never wait on HBM.
// Requires nk >= 2 (all uses have nk >= 16).
template <typename OutT, int MODE>
__global__ __launch_bounds__(512) void gemmA(
    const bf16* __restrict__ A, int lda,
    const bf16* __restrict__ Bt, long bzs, int ldb,
    OutT* __restrict__ C, int ldc,
    const float* __restrict__ bias0, const float* __restrict__ bias1,
    const float* __restrict__ bias2, float alpha, int K) {
  __shared__ __align__(16) bf16 As[2][2][256 * 32];
  __shared__ __align__(16) bf16 Bs[2][2][128 * 32];
  const int tid = threadIdx.x;
  const int lane = tid & 63;
  const int w = tid >> 6;
  const int wm = w & 3;   // wave-row: rows wm*64..+64
  const int wn = w >> 2;  // wave-col: cols wn*64..+64
  const int quad = lane >> 4;
  const int l15 = lane & 15;
  // swizzled frag slot: (row>>1)&3 == (l15>>1)&3 for all frag rows -> lane-const
  const int fse = (quad ^ ((l15 >> 1) & 3)) << 3;

  // GROUP-8 M-swizzle for XCD/L2 locality (gridDim.y = 32 in all launches)
  const int gx = gridDim.x;
  const int pid = blockIdx.y * gx + blockIdx.x;
  const int gsz = 8 * gx;
  const int bym = (pid / gsz) * 8 + (pid % 8);
  const int bxm = (pid % gsz) / 8;
  const int row0 = bym * 256;
  const int col0 = bxm * 128;

  const bf16* Arow = A + (long)row0 * lda;
  const bf16* Bcol;
  int grp = 0;
  if (MODE == MODE_QKV) {
    grp = col0 >> 10;  // 128-col tile never straddles a 1024 group boundary
    Bcol = Bt + (long)grp * ((long)D_ * D_) + (long)(col0 & (D_ - 1)) * ldb;
  } else if (MODE == MODE_PV) {
    Bcol = Bt + (long)(row0 >> 11) * bzs + (long)col0 * ldb;
  } else {
    Bcol = Bt + (long)col0 * ldb;
  }

  f32x4 acc[4][4];
#pragma unroll
  for (int i = 0; i < 4; ++i)
#pragma unroll
    for (int j = 0; j < 4; ++j) acc[i][j] = (f32x4){0.f, 0.f, 0.f, 0.f};

  const int nk = K >> 6;

  // prologue: tile 0 (kh0,kh1) + kh0 of tile 1; retire tile 0 only (vmcnt(3)).
  stage256(Arow, lda, 0, &As[0][0][0], tid);
  stage128(Bcol, ldb, 0, &Bs[0][0][0], tid);
  stage256(Arow, lda, 32, &As[0][1][0], tid);
  stage128(Bcol, ldb, 32, &Bs[0][1][0], tid);
  stage256(Arow, lda, 64, &As[1][0][0], tid);
  stage128(Bcol, ldb, 64, &Bs[1][0][0], tid);
  asm volatile("s_waitcnt vmcnt(3)" ::: "memory");
  __builtin_amdgcn_s_barrier();
  __builtin_amdgcn_sched_barrier(0);

  for (int t = 0; t < nk; ++t) {
    const int buf = t & 1;
    bf16x8 af[4], bf[4];

    // ---- P1: ks0 ----
#pragma unroll
    for (int j = 0; j < 4; ++j) {
      af[j] = *(const bf16x8*)&As[buf][0][(wm * 64 + j * 16 + l15) * 32 + fse];
      bf[j] = *(const bf16x8*)&Bs[buf][0][(wn * 64 + j * 16 + l15) * 32 + fse];
    }
    if (t + 1 < nk) {
      const int kt = ((t + 1) << 6) + 32;
      stage256(Arow, lda, kt, &As[buf ^ 1][1][0], tid);
      stage128(Bcol, ldb, kt, &Bs[buf ^ 1][1][0], tid);
    }
    __builtin_amdgcn_s_setprio(1);
#pragma unroll
    for (int mi = 0; mi < 4; ++mi)
#pragma unroll
      for (int ni = 0; ni < 4; ++ni)
        acc[mi][ni] = __builtin_amdgcn_mfma_f32_16x16x32_bf16(af[mi], bf[ni], acc[mi][ni], 0, 0, 0);
    __builtin_amdgcn_s_setprio(0);
    if (t + 1 < nk)
      asm volatile("s_waitcnt vmcnt(6)" ::: "memory");
    else
      asm volatile("s_waitcnt vmcnt(0)" ::: "memory");
    __builtin_amdgcn_s_barrier();
    __builtin_amdgcn_sched_barrier(0);

    // ---- P2: ks1 ----
#pragma unroll
    for (int j = 0; j < 4; ++j) {
      af[j] = *(const bf16x8*)&As[buf][1][(wm * 64 + j * 16 + l15) * 32 + fse];
      bf[j] = *(const bf16x8*)&Bs[buf][1][(wn * 64 + j * 16 + l15) * 32 + fse];
    }
    if (t + 2 < nk) {
      const int kt = (t + 2) << 6;
      stage256(Arow, lda, kt, &As[buf][0][0], tid);
      stage128(Bcol, ldb, kt, &Bs[buf][0][0], tid);
    }
    __builtin_amdgcn_s_setprio(1);
#pragma unroll
    for (int mi = 0; mi < 4; ++mi)
#pragma unroll
      for (int ni = 0; ni < 4; ++ni)
        acc[mi][ni] = __builtin_amdgcn_mfma_f32_16x16x32_bf16(af[mi], bf[ni], acc[mi][ni], 0, 0, 0);
    __builtin_amdgcn_s_setprio(0);
    if (t + 2 < nk)
      asm volatile("s_waitcnt vmcnt(6)" ::: "memory");
    else if (t + 1 < nk)
      asm volatile("s_waitcnt vmcnt(3)" ::: "memory");
    __builtin_amdgcn_s_barrier();
    __builtin_amdgcn_sched_barrier(0);
  }

  // epilogue: C/D layout col = lane&15, row = quad*4 + reg
  const float* bias = (MODE == MODE_QKV)
                          ? (grp == 0 ? bias0 : grp == 1 ? bias1 : bias2)
                          : bias0;
  const long NX = (long)B_ * S_ * D_;
  OutT* Cb = (MODE == MODE_QKV) ? C + (long)grp * NX : C;
#pragma unroll
  for (int mi = 0; mi < 4; ++mi)
#pragma unroll
    for (int ni = 0; ni < 4; ++ni) {
      const int col = col0 + wn * 64 + ni * 16 + l15;
      const int ccol = (MODE == MODE_QKV) ? (col & (D_ - 1)) : col;
      const float bv = bias ? bias[ccol] : 0.0f;
#pragma unroll
      for (int r = 0; r < 4; ++r) {
        const int row = row0 + wm * 64 + mi * 16 + quad * 4 + r;
        const float val = acc[mi][ni][r] * alpha + bv;
        if (MODE == MODE_QKV) {
          Cb[(long)row * D_ + ccol] = (OutT)val;
        } else {
          Cb[(long)row * ldc + col] = (OutT)val;
        }
      }
    }
}

// ---------------- 256^2 4-phase single-barrier counted-vmcnt GEMM (EXP) ----------------
__device__ __forceinline__ void stage_half(const bf16* __restrict__ G, int ld,
                                           int row_base, int kcol,
                                           bf16* region, int tid) {
  const int r = tid >> 2;
  const int c = ((tid & 3) ^ ((tid >> 3) & 3)) << 3;
  const bf16* g = G + (long)(row_base + r) * ld + kcol + c;
  bf16* dst = region + ((tid >> 6) << 9);
  async_copy16(g, dst);
  async_copy16(g + (long)128 * ld, dst + 4096);
}

template <typename OutT, int MODE>
__global__ __launch_bounds__(512) void gemm256(
    const bf16* __restrict__ A, long aB, int lda,
    const bf16* __restrict__ Bt, long bB, int ldb,
    OutT* __restrict__ C, long cB, int ldc,
    const float* __restrict__ bias0, const float* __restrict__ bias1,
    const float* __restrict__ bias2, float alpha, int K) {
  __shared__ __align__(16) bf16 As[2][2][256 * 32];
  __shared__ __align__(16) bf16 Bs[2][2][256 * 32];
  const int tid = threadIdx.x;
  const int lane = tid & 63;
  const int w = tid >> 6;
  const int wm = w & 1;
  const int wn = w >> 1;
  const int quad = lane >> 4;
  const int l15 = lane & 15;
  const int fse = (quad ^ ((l15 >> 1) & 3)) << 3;

  A += (long)blockIdx.z * aB;
  Bt += (long)blockIdx.z * bB;
  if (MODE != MODE_QKV) C += (long)blockIdx.z * cB;

  const int gx = gridDim.x;
  const int pid = blockIdx.y * gx + blockIdx.x;
  const int gsz = 8 * gx;
  const int bym = (pid / gsz) * 8 + (pid % 8);
  const int bxm = (pid % gsz) / 8;
  const int row0 = bym * 256;
  const int col0 = bxm * 256;

  f32x4 acc[8][4];
#pragma unroll
  for (int i = 0; i < 8; ++i)
#pragma unroll
    for (int j = 0; j < 4; ++j) acc[i][j] = (f32x4){0.f, 0.f, 0.f, 0.f};

  const int nk = K >> 6;

  stage_half(A, lda, row0, 0, &As[0][0][0], tid);
  stage_half(Bt, ldb, col0, 0, &Bs[0][0][0], tid);
  stage_half(A, lda, row0, 32, &As[0][1][0], tid);
  stage_half(Bt, ldb, col0, 32, &Bs[0][1][0], tid);
  if (nk > 1) {
    stage_half(A, lda, row0, 64, &As[1][0][0], tid);
    stage_half(Bt, ldb, col0, 64, &Bs[1][0][0], tid);
    asm volatile("s_waitcnt vmcnt(4)" ::: "memory");
  } else {
    asm volatile("s_waitcnt vmcnt(0)" ::: "memory");
  }
  __builtin_amdgcn_s_barrier();
  __builtin_amdgcn_sched_barrier(0);

  for (int t = 0; t < nk; ++t) {
    const int buf = t & 1;
    bf16x8 af[8], b0, b1;

    // ---- P1: ks0, n{0,1} ----
#pragma unroll
    for (int m = 0; m < 8; ++m)
      af[m] = *(const bf16x8*)&As[buf][0][(wm * 128 + m * 16 + l15) * 32 + fse];
    b0 = *(const bf16x8*)&Bs[buf][0][(wn * 64 + l15) * 32 + fse];
    b1 = *(const bf16x8*)&Bs[buf][0][(wn * 64 + 16 + l15) * 32 + fse];
    if (t + 1 < nk)
      stage_half(A, lda, row0, ((t + 1) << 6) + 32, &As[buf ^ 1][1][0], tid);
    __builtin_amdgcn_s_setprio(1);
#pragma unroll
    for (int m = 0; m < 8; ++m) {
      acc[m][0] = __builtin_amdgcn_mfma_f32_16x16x32_bf16(af[m], b0, acc[m][0], 0, 0, 0);
      acc[m][1] = __builtin_amdgcn_mfma_f32_16x16x32_bf16(af[m], b1, acc[m][1], 0, 0, 0);
    }
    __builtin_amdgcn_s_setprio(0);
    __builtin_amdgcn_s_barrier();
    __builtin_amdgcn_sched_barrier(0);

    // ---- P2: ks0, n{2,3} ----
    b0 = *(const bf16x8*)&Bs[buf][0][(wn * 64 + 32 + l15) * 32 + fse];
    b1 = *(const bf16x8*)&Bs[buf][0][(wn * 64 + 48 + l15) * 32 + fse];
    if (t + 1 < nk)
      stage_half(Bt, ldb, col0, ((t + 1) << 6) + 32, &Bs[buf ^ 1][1][0], tid);
    __builtin_amdgcn_s_setprio(1);
#pragma unroll
    for (int m = 0; m < 8; ++m) {
      acc[m][2] = __builtin_amdgcn_mfma_f32_16x16x32_bf16(af[m], b0, acc[m][2], 0, 0, 0);
      acc[m][3] = __builtin_amdgcn_mfma_f32_16x16x32_bf16(af[m], b1, acc[m][3], 0, 0, 0);
    }
    __builtin_amdgcn_s_setprio(0);
    __builtin_amdgcn_s_barrier();
    __builtin_amdgcn_sched_barrier(0);

    // ---- P3: ks1, n{0,1} ----
#pragma unroll
    for (int m = 0; m < 8; ++m)
      af[m] = *(const bf16x8*)&As[buf][1][(wm * 128 + m * 16 + l15) * 32 + fse];
    b0 = *(const bf16x8*)&Bs[buf][1][(wn * 64 + l15) * 32 + fse];
    b1 = *(const bf16x8*)&Bs[buf][1][(wn * 64 + 16 + l15) * 32 + fse];
    if (t + 2 < nk)
      stage_half(A, lda, row0, (t + 2) << 6, &As[buf][0][0], tid);
    __builtin_amdgcn_s_setprio(1);
#pragma unroll
    for (int m = 0; m < 8; ++m) {
      acc[m][0] = __builtin_amdgcn_mfma_f32_16x16x32_bf16(af[m], b0, acc[m][0], 0, 0, 0);
      acc[m][1] = __builtin_amdgcn_mfma_f32_16x16x32_bf16(af[m], b1, acc[m][1], 0, 0, 0);
    }
    __builtin_amdgcn_s_setprio(0);
    __builtin_amdgcn_s_barrier();
    __builtin_amdgcn_sched_barrier(0);

    // ---- P4: ks1, n{2,3} ----
    b0 = *(const bf16x8*)&Bs[buf][1][(wn * 64 + 32 + l15) * 32 + fse];
    b1 = *(const bf16x8*)&Bs[buf][1][(wn * 64 + 48 + l15) * 32 + fse];
    if (t + 2 < nk)
      stage_half(Bt, ldb, col0, (t + 2) << 6, &Bs[buf][0][0], tid);
    if (t + 2 < nk)
      asm volatile("s_waitcnt vmcnt(4)" ::: "memory");
    else
      asm volatile("s_waitcnt vmcnt(0)" ::: "memory");
    __builtin_amdgcn_s_setprio(1);
#pragma unroll
    for (int m = 0; m < 8; ++m) {
      acc[m][2] = __builtin_amdgcn_mfma_f32_16x16x32_bf16(af[m], b0, acc[m][2], 0, 0, 0);
      acc[m][3] = __builtin_amdgcn_mfma_f32_16x16x32_bf16(af[m], b1, acc[m][3], 0, 0, 0);
    }
    __builtin_amdgcn_s_setprio(0);
    __builtin_amdgcn_s_barrier();
    __builtin_amdgcn_sched_barrier(0);
  }

  const int grp = (MODE == MODE_QKV) ? (bxm >> 2) : 0;
  const float* bias = (MODE == MODE_QKV)
                          ? (grp == 0 ? bias0 : grp == 1 ? bias1 : bias2)
                          : bias0;
  const long NX = (long)B_ * S_ * D_;
#pragma unroll
  for (int mi = 0; mi < 8; ++mi)
#pragma unroll
    for (int ni = 0; ni < 4; ++ni) {
      const int col = col0 + wn * 64 + ni * 16 + l15;
      const int lcol = col & (D_ - 1);
      const float bv = bias ? bias[MODE == MODE_QKV ? lcol : col] : 0.0f;
#pragma unroll
      for (int r = 0; r < 4; ++r) {
        const int row = row0 + wm * 128 + mi * 16 + quad * 4 + r;
        const float val = acc[mi][ni][r] * alpha + bv;
        if (MODE == MODE_EXP) {
          C[(long)row * ldc + col] = (OutT)__expf(val);
        } else if (MODE == MODE_QKV) {
          C[grp * NX + (long)row * D_ + lcol] = (OutT)val;
        } else {
          C[(long)row * ldc + col] = (OutT)val;
        }
      }
    }
}

// grid (S, B): P[b,q,:] = E[b,q,:] * sum_m bit_m(q,:) / rowsum_m / M, bf16.
__global__ __launch_bounds__(256) void softmax_combine(
    const f16* __restrict__ E, const u8* __restrict__ pk, bf16* __restrict__ P) {
  const int q = blockIdx.x;
  const int b = blockIdx.y;
  const int tid = threadIdx.x;
  const int lane = tid & 63;
  const int wv = tid >> 6;
  __shared__ float4 red[4];

  float e[8];
  {
    const f16x8 h = *(const f16x8*)(E + ((long)b * S_ + q) * S_ + tid * 8);
#pragma unroll
    for (int j = 0; j < 8; ++j) e[j] = (float)h[j];
  }
  const unsigned long long mb =
      *(const unsigned long long*)(pk + (long)q * S_ + tid * 8);

  float4 s = {0.f, 0.f, 0.f, 0.f};
#pragma unroll
  for (int j = 0; j < 8; ++j) {
    const unsigned bits = (unsigned)(mb >> (8 * j)) & 0xF;
    const float ev = e[j];
    if (bits & 1) s.x += ev;
    if (bits & 2) s.y += ev;
    if (bits & 4) s.z += ev;
    if (bits & 8) s.w += ev;
  }
#pragma unroll
  for (int o = 32; o > 0; o >>= 1) {
    s.x += __shfl_xor(s.x, o, 64);
    s.y += __shfl_xor(s.y, o, 64);
    s.z += __shfl_xor(s.z, o, 64);
    s.w += __shfl_xor(s.w, o, 64);
  }
  if (lane == 0) red[wv] = s;
  __syncthreads();
  const float4 t0 = red[0], t1 = red[1], t2 = red[2], t3 = red[3];
  const float r0 = 0.25f / (t0.x + t1.x + t2.x + t3.x);
  const float r1 = 0.25f / (t0.y + t1.y + t2.y + t3.y);
  const float r2 = 0.25f / (t0.z + t1.z + t2.z + t3.z);
  const float r3 = 0.25f / (t0.w + t1.w + t2.w + t3.w);

  bf16x8 o;
#pragma unroll
  for (int j = 0; j < 8; ++j) {
    const unsigned bits = (unsigned)(mb >> (8 * j)) & 0xF;
    const float wgt = ((bits & 1) ? r0 : 0.f) + ((bits & 2) ? r1 : 0.f) +
                      ((bits & 4) ? r2 : 0.f) + ((bits & 8) ? r3 : 0.f);
    o[j] = (bf16)(e[j] * wgt);
  }
  *(bf16x8*)(P + ((long)b * S_ + q) * S_ + tid * 8) = o;
}

extern "C" void kernel_launch(void* const* d_in, const int* in_sizes, int n_in,
                              void* d_out, int out_size, void* d_ws, size_t ws_size,
                              hipStream_t stream) {
  const float* x = (const float*)d_in[0];
  const int* masks = (const int*)d_in[1];
  const float* bq = (const float*)d_in[3];
  const float* bk = (const float*)d_in[5];
  const float* bv = (const float*)d_in[7];
  const float* bo = (const float*)d_in[9];
  float* out = (float*)d_out;

  const long DD = (long)D_ * D_;
  const long SD = (long)S_ * D_;
  const long NX = (long)B_ * SD;
  const long SS = (long)S_ * S_;

  // ws: xc 16M | WT 8M | pk 4M | Q/K/V 48M | VT 16M | P 32M | E 32M = 156 MiB
  bf16* xc = (bf16*)d_ws;
  bf16* WqT = xc + NX;  // WkT, WvT, WoT contiguous after
  bf16* WoT = WqT + 3 * DD;
  u8* pk = (u8*)(WoT + DD);    // [S][S] mask bitfield
  bf16* Q = (bf16*)(pk + SS);  // K = Q+NX, V = K+NX (QKV epilogue relies on it)
  bf16* K = Q + NX;
  bf16* V = K + NX;
  bf16* VT = V + NX;
  bf16* P = VT + NX;                   // [B][S][S] bf16
  f16* E = (f16*)(P + (long)B_ * SS);  // [B][S][S] f16
  bf16* attn = Q;                      // attn overwrites dead Q

  dim3 blk(256);
  dim3 blk512(512);

  // fused prep: x->bf16, 4 weight transposes, mask pack (one launch)
  prep<<<dim3(7168), blk, 0, stream>>>(
      x, (const float*)d_in[2], (const float*)d_in[4], (const float*)d_in[6],
      (const float*)d_in[8], masks, xc, WqT, pk);

  // fused Q|K|V projection: [8192,1024] x [1024,3072], 256x128 tiles
  // grid 24x32 = 768 blocks = 3 exact rounds
  gemmA<bf16, MODE_QKV><<<dim3(24, 32), blk512, 0, stream>>>(
      xc, D_, WqT, 0, D_, Q, D_, bq, bk, bv, 1.0f, D_);

  // VT[b][d][s] = V[b][s][d]
  transposeB<<<dim3(16, 32, B_), blk, 0, stream>>>(V, VT, S_, D_, SD, SD);

  // E = exp(Q K^T / 32) : [B][2048][2048] f16 (256^2 4-phase, 256 blocks = 1 round)
  gemm256<f16, MODE_EXP><<<dim3(8, 8, B_), blk512, 0, stream>>>(
      Q, SD, D_, K, SD, D_, E, SS, S_, nullptr, nullptr, nullptr, 1.0f / 32.0f, D_);

  // P = E * sum_m mask_m / rowsum_m / M
  softmax_combine<<<dim3(S_, B_), blk, 0, stream>>>(E, pk, P);

  // attn = P @ V : flat [8192,2048] x VT[z][1024,2048], K=2048
  // grid 8x32 = 256 blocks = 1 exact round
  gemmA<bf16, MODE_PV><<<dim3(8, 32), blk512, 0, stream>>>(
      P, S_, VT, SD, S_, attn, D_, nullptr, nullptr, nullptr, 1.0f, S_);

  // out = attn @ Wo + bo : fp32 epilogue straight to d_out (256 blocks = 1 round)
  gemmA<float, MODE_PLAIN><<<dim3(8, 32), blk512, 0, stream>>>(
      attn, D_, WoT, 0, D_, out, D_, bo, nullptr, nullptr, 1.0f, D_);
}

// Round 8
// 350.844 us; speedup vs baseline: 1.0428x; 1.0290x over previous
//
#include <hip/hip_runtime.h>
#include <hip/hip_bf16.h>
#include <stdint.h>

#define B_ 4
#define S_ 2048
#define D_ 1024
#define M_ 4

typedef __bf16 bf16;
typedef _Float16 f16;
typedef unsigned char u8;
typedef __bf16 bf16x8 __attribute__((ext_vector_type(8)));
typedef _Float16 f16x8 __attribute__((ext_vector_type(8)));
typedef float f32x4 __attribute__((ext_vector_type(4)));

__device__ __forceinline__ void async_copy16(const void* g, void* l) {
  __builtin_amdgcn_global_load_lds(
      (const __attribute__((address_space(1))) void*)g,
      (__attribute__((address_space(3))) void*)l, 16, 0, 0);
}

// Fused prep, block ranges:
//   [0,4096)      : x fp32 -> bf16
//   [4096,5120)   : 4x W [1024,1024] fp32 -> WT bf16 (256 blocks each)
//   [5120,7168)   : pack 4 masks -> bitfield bytes
__global__ __launch_bounds__(256) void prep(
    const float* __restrict__ x, const float* __restrict__ w0,
    const float* __restrict__ w1, const float* __restrict__ w2,
    const float* __restrict__ w3, const int* __restrict__ masks,
    bf16* __restrict__ xc, bf16* __restrict__ WT, u8* __restrict__ pk) {
  __shared__ bf16 t[64][65];
  const int blk = blockIdx.x;
  const int tid = threadIdx.x;
  const long SS = (long)S_ * S_;

  if (blk < 4096) {  // x -> bf16
    const long i = (long)blk * 2048 + tid * 8;
    const float4 a = *(const float4*)(x + i);
    const float4 b = *(const float4*)(x + i + 4);
    bf16x8 o;
    o[0] = (bf16)a.x; o[1] = (bf16)a.y; o[2] = (bf16)a.z; o[3] = (bf16)a.w;
    o[4] = (bf16)b.x; o[5] = (bf16)b.y; o[6] = (bf16)b.z; o[7] = (bf16)b.w;
    *(bf16x8*)(xc + i) = o;
  } else if (blk < 5120) {  // weight transpose -> bf16
    const int local = blk - 4096;
    const int z = local >> 8;
    const int rem = local & 255;
    const int r0 = (rem >> 4) * 64;
    const int c0 = (rem & 15) * 64;
    const int tx = tid & 63;
    const int ty = tid >> 6;
    const float* in = (z == 0) ? w0 : (z == 1) ? w1 : (z == 2) ? w2 : w3;
    bf16* out = WT + (long)z * D_ * D_;
    for (int i = ty; i < 64; i += 4)
      t[i][tx] = (bf16)in[(long)(r0 + i) * D_ + c0 + tx];
    __syncthreads();
    for (int i = ty; i < 64; i += 4)
      out[(long)(c0 + i) * D_ + r0 + tx] = t[tx][i];
  } else {  // pack masks
    const long e = (long)(blk - 5120) * 2048 + tid * 8;
    unsigned long long wv = 0;
#pragma unroll
    for (int m = 0; m < M_; ++m) {
      const int4 a = *(const int4*)(masks + m * SS + e);
      const int4 b = *(const int4*)(masks + m * SS + e + 4);
      const int v[8] = {a.x, a.y, a.z, a.w, b.x, b.y, b.z, b.w};
#pragma unroll
      for (int j = 0; j < 8; ++j)
        wv |= (unsigned long long)(v[j] != 0 ? 1u : 0u) << (8 * j + m);
    }
    *(unsigned long long*)(pk + e) = wv;
  }
}

// batched bf16 [rows,cols] -> [cols,rows] transpose (z = batch)
__global__ __launch_bounds__(256) void transposeB(
    const bf16* __restrict__ in, bf16* __restrict__ out,
    int rows, int cols, long ib, long ob) {
  __shared__ bf16 t[64][65];
  in += (long)blockIdx.z * ib;
  out += (long)blockIdx.z * ob;
  const int r0 = blockIdx.y * 64;
  const int c0 = blockIdx.x * 64;
  const int tx = threadIdx.x & 63;
  const int ty = threadIdx.x >> 6;
#pragma unroll
  for (int i = ty; i < 64; i += 4) t[i][tx] = in[(long)(r0 + i) * cols + c0 + tx];
  __syncthreads();
#pragma unroll
  for (int i = ty; i < 64; i += 4) out[(long)(c0 + i) * rows + r0 + tx] = t[tx][i];
}

#define MODE_PLAIN 0
#define MODE_EXP 1   // C = exp(alpha*acc), f16 out; B z-batched by row0>>11
#define MODE_QKV 2   // N=3072 grouped epilogue: Q | K | V
#define MODE_PV 3    // B z-batched by row0>>11

// ---------- 256x128 3-slot rotating counted-vmcnt GEMM, 2 blocks/CU ----------
// 512 threads = 8 waves (4M x 2N), per-wave output 64x64 (acc 4x4).
// LDS: As[3][256*32] 48K + Bs[3][128*32] 24K = 72 KiB -> 2 blocks/CU (was 96K,
// 1 block/CU). Rationale: r2-r4 showed intra-block LDS/MFMA overlap is not
// reachable at HIP source level (phase = LDS 768 + MFMA 621 + sync ~500 cyc,
// serial, MfmaUtil 27-29% across three schedule variants; the sched_barrier-
// enforced variant is hang-suspect). Cross-BLOCK overlap is the documented
// working mechanism (m97: 874 TF at 2-3 blocks/CU with no explicit pipelining):
// while this block's waves are in their LDS-read/stage phase, the co-resident
// block's waves feed the MFMA pipe.
// K split into nh = K/32 halves; half h lives in slot h%3.
// Phase h: {READF(slot h%3) | STAGE(half h+2 -> slot (h+2)%3) | 16 MFMA
//           | publish half h+1: vmcnt(3) | s_barrier | sched_barrier}
// vmcnt ledger (3 loads/stage: A x2 + B x1, per thread): at publish of h+1,
// outstanding = {h+1 (issued phase h-1), h+2 (issued phase h)} = 6 -> vmcnt(3)
// retires h+1. Tail: h = nh-2 publishes nh-1 with vmcnt(0) (nothing staged in
// that phase); final phase has no wait/barrier. Prologue stages halves 0,1 ->
// vmcnt(3) publishes half 0.
// WAR: STAGE(h+2) overwrites slot of half h-1, whose reads completed before
// the end-of-phase-(h-1) barrier (all reads are consumed by MFMAs in their own
// phase -> lgkm-drained pre-barrier); the stage is issued after that barrier
// (sched_barrier pins it below). Cross-wave RAW: per-wave vmcnt precedes the
// barrier -> barrier-exit implies all waves' DMA for the published half retired.
// Swizzle (validated r1-r7): 16B slot stored at slot^((row>>1)&3) via
// pre-swizzled GLOBAL source + linear LDS dest + swizzled ds_read; conflicts=0.
// Requires nh >= 3 (all uses have nh >= 32).
template <typename OutT, int MODE>
__global__ __launch_bounds__(512) void gemmA(
    const bf16* __restrict__ A, int lda,
    const bf16* __restrict__ Bt, long bzs, int ldb,
    OutT* __restrict__ C, int ldc,
    const float* __restrict__ bias0, const float* __restrict__ bias1,
    const float* __restrict__ bias2, float alpha, int K) {
  __shared__ __align__(16) bf16 As[3][256 * 32];
  __shared__ __align__(16) bf16 Bs[3][128 * 32];
  const int tid = threadIdx.x;
  const int lane = tid & 63;
  const int w = tid >> 6;
  const int wm = w & 3;   // wave-row: rows wm*64..+64
  const int wn = w >> 2;  // wave-col: cols wn*64..+64
  const int quad = lane >> 4;
  const int l15 = lane & 15;
  // swizzled frag slot: (row>>1)&3 == (l15>>1)&3 for all frag rows -> lane-const
  const int fse = (quad ^ ((l15 >> 1) & 3)) << 3;

  // GROUP-8 M-swizzle for XCD/L2 locality (gridDim.y = 32 in all launches)
  const int gx = gridDim.x;
  const int pid = blockIdx.y * gx + blockIdx.x;
  const int gsz = 8 * gx;
  const int bym = (pid / gsz) * 8 + (pid % 8);
  const int bxm = (pid % gsz) / 8;
  const int row0 = bym * 256;
  const int col0 = bxm * 128;

  const bf16* Arow = A + (long)row0 * lda;
  const bf16* Bcol;
  int grp = 0;
  if (MODE == MODE_QKV) {
    grp = col0 >> 10;  // 128-col tile never straddles a 1024 group boundary
    Bcol = Bt + (long)grp * ((long)D_ * D_) + (long)(col0 & (D_ - 1)) * ldb;
  } else if (MODE == MODE_PV || MODE == MODE_EXP) {
    Bcol = Bt + (long)(row0 >> 11) * bzs + (long)col0 * ldb;
  } else {
    Bcol = Bt + (long)col0 * ldb;
  }

  // per-thread staging constants (pre-swizzled global source)
  const int sr = tid >> 2;                             // row 0..127
  const int sc = ((tid & 3) ^ ((tid >> 3) & 3)) << 3;  // swizzled 16B slot
  const bf16* gA = Arow + (long)sr * lda + sc;
  const bf16* gB = Bcol + (long)sr * ldb + sc;
  const int dstoff = (tid >> 6) << 9;  // wave-uniform base (elems)
  const long a128 = (long)128 * lda;

#define STAGE(h, s)                                                    \
  {                                                                    \
    const int kc_ = (h) * 32;                                          \
    bf16* da_ = &As[0][0] + (s) * (256 * 32) + dstoff;                 \
    bf16* db_ = &Bs[0][0] + (s) * (128 * 32) + dstoff;                 \
    async_copy16(gA + kc_, da_);                                       \
    async_copy16(gA + kc_ + a128, da_ + 4096);                         \
    async_copy16(gB + kc_, db_);                                       \
  }

#define READF(Ra, Rb, s)                                                   \
  {                                                                        \
    const bf16* pa_ = &As[0][0] + (s) * (256 * 32);                        \
    const bf16* pb_ = &Bs[0][0] + (s) * (128 * 32);                        \
    _Pragma("unroll") for (int j = 0; j < 4; ++j) {                        \
      Ra[j] = *(const bf16x8*)&pa_[(wm * 64 + j * 16 + l15) * 32 + fse];   \
      Rb[j] = *(const bf16x8*)&pb_[(wn * 64 + j * 16 + l15) * 32 + fse];   \
    }                                                                      \
  }

#define MM(Ra, Rb)                                                         \
  __builtin_amdgcn_s_setprio(1);                                           \
  _Pragma("unroll") for (int mi = 0; mi < 4; ++mi)                         \
      _Pragma("unroll") for (int ni = 0; ni < 4; ++ni) acc[mi][ni] =       \
          __builtin_amdgcn_mfma_f32_16x16x32_bf16(Ra[mi], Rb[ni],          \
                                                  acc[mi][ni], 0, 0, 0);   \
  __builtin_amdgcn_s_setprio(0);

  f32x4 acc[4][4];
#pragma unroll
  for (int i = 0; i < 4; ++i)
#pragma unroll
    for (int j = 0; j < 4; ++j) acc[i][j] = (f32x4){0.f, 0.f, 0.f, 0.f};

  const int nh = (K >> 6) << 1;  // number of 32-col K-halves

  // prologue: stage halves 0,1; publish half 0 (outstanding 6, retire 3).
  STAGE(0, 0);
  STAGE(1, 1);
  asm volatile("s_waitcnt vmcnt(3)" ::: "memory");
  __builtin_amdgcn_s_barrier();
  __builtin_amdgcn_sched_barrier(0);

  int s0 = 0;  // h % 3
  for (int h = 0; h < nh; ++h) {
    bf16x8 af[4], bf[4];
    READF(af, bf, s0);
    if (h + 2 < nh) {
      const int s2 = (s0 >= 1) ? (s0 - 1) : 2;  // (h+2) % 3
      STAGE(h + 2, s2);
    }
    MM(af, bf);
    if (h + 2 < nh)
      asm volatile("s_waitcnt vmcnt(3)" ::: "memory");
    else if (h + 1 < nh)
      asm volatile("s_waitcnt vmcnt(0)" ::: "memory");
    if (h + 1 < nh) {
      __builtin_amdgcn_s_barrier();
      __builtin_amdgcn_sched_barrier(0);
    }
    s0 = (s0 == 2) ? 0 : (s0 + 1);
  }

#undef STAGE
#undef READF
#undef MM

  // epilogue: C/D layout col = lane&15, row = quad*4 + reg
  const float* bias = (MODE == MODE_QKV)
                          ? (grp == 0 ? bias0 : grp == 1 ? bias1 : bias2)
                          : bias0;
  const long NX = (long)B_ * S_ * D_;
  OutT* Cb = (MODE == MODE_QKV) ? C + (long)grp * NX : C;
#pragma unroll
  for (int mi = 0; mi < 4; ++mi)
#pragma unroll
    for (int ni = 0; ni < 4; ++ni) {
      const int col = col0 + wn * 64 + ni * 16 + l15;
      const int ccol = (MODE == MODE_QKV) ? (col & (D_ - 1)) : col;
      const float bv = bias ? bias[ccol] : 0.0f;
#pragma unroll
      for (int r = 0; r < 4; ++r) {
        const int row = row0 + wm * 64 + mi * 16 + quad * 4 + r;
        const float val = acc[mi][ni][r] * alpha + bv;
        if (MODE == MODE_EXP) {
          Cb[(long)row * ldc + col] = (OutT)__expf(val);
        } else if (MODE == MODE_QKV) {
          Cb[(long)row * D_ + ccol] = (OutT)val;
        } else {
          Cb[(long)row * ldc + col] = (OutT)val;
        }
      }
    }
}

// grid (S, B): P[b,q,:] = E[b,q,:] * sum_m bit_m(q,:) / rowsum_m / M, bf16.
__global__ __launch_bounds__(256) void softmax_combine(
    const f16* __restrict__ E, const u8* __restrict__ pk, bf16* __restrict__ P) {
  const int q = blockIdx.x;
  const int b = blockIdx.y;
  const int tid = threadIdx.x;
  const int lane = tid & 63;
  const int wv = tid >> 6;
  __shared__ float4 red[4];

  float e[8];
  {
    const f16x8 h = *(const f16x8*)(E + ((long)b * S_ + q) * S_ + tid * 8);
#pragma unroll
    for (int j = 0; j < 8; ++j) e[j] = (float)h[j];
  }
  const unsigned long long mb =
      *(const unsigned long long*)(pk + (long)q * S_ + tid * 8);

  float4 s = {0.f, 0.f, 0.f, 0.f};
#pragma unroll
  for (int j = 0; j < 8; ++j) {
    const unsigned bits = (unsigned)(mb >> (8 * j)) & 0xF;
    const float ev = e[j];
    if (bits & 1) s.x += ev;
    if (bits & 2) s.y += ev;
    if (bits & 4) s.z += ev;
    if (bits & 8) s.w += ev;
  }
#pragma unroll
  for (int o = 32; o > 0; o >>= 1) {
    s.x += __shfl_xor(s.x, o, 64);
    s.y += __shfl_xor(s.y, o, 64);
    s.z += __shfl_xor(s.z, o, 64);
    s.w += __shfl_xor(s.w, o, 64);
  }
  if (lane == 0) red[wv] = s;
  __syncthreads();
  const float4 t0 = red[0], t1 = red[1], t2 = red[2], t3 = red[3];
  const float r0 = 0.25f / (t0.x + t1.x + t2.x + t3.x);
  const float r1 = 0.25f / (t0.y + t1.y + t2.y + t3.y);
  const float r2 = 0.25f / (t0.z + t1.z + t2.z + t3.z);
  const float r3 = 0.25f / (t0.w + t1.w + t2.w + t3.w);

  bf16x8 o;
#pragma unroll
  for (int j = 0; j < 8; ++j) {
    const unsigned bits = (unsigned)(mb >> (8 * j)) & 0xF;
    const float wgt = ((bits & 1) ? r0 : 0.f) + ((bits & 2) ? r1 : 0.f) +
                      ((bits & 4) ? r2 : 0.f) + ((bits & 8) ? r3 : 0.f);
    o[j] = (bf16)(e[j] * wgt);
  }
  *(bf16x8*)(P + ((long)b * S_ + q) * S_ + tid * 8) = o;
}

extern "C" void kernel_launch(void* const* d_in, const int* in_sizes, int n_in,
                              void* d_out, int out_size, void* d_ws, size_t ws_size,
                              hipStream_t stream) {
  const float* x = (const float*)d_in[0];
  const int* masks = (const int*)d_in[1];
  const float* bq = (const float*)d_in[3];
  const float* bk = (const float*)d_in[5];
  const float* bv = (const float*)d_in[7];
  const float* bo = (const float*)d_in[9];
  float* out = (float*)d_out;

  const long DD = (long)D_ * D_;
  const long SD = (long)S_ * D_;
  const long NX = (long)B_ * SD;
  const long SS = (long)S_ * S_;

  // ws: xc 16M | WT 8M | pk 4M | Q/K/V 48M | VT 16M | P 32M | E 32M = 156 MiB
  bf16* xc = (bf16*)d_ws;
  bf16* WqT = xc + NX;  // WkT, WvT, WoT contiguous after
  bf16* WoT = WqT + 3 * DD;
  u8* pk = (u8*)(WoT + DD);    // [S][S] mask bitfield
  bf16* Q = (bf16*)(pk + SS);  // K = Q+NX, V = K+NX (QKV epilogue relies on it)
  bf16* K = Q + NX;
  bf16* V = K + NX;
  bf16* VT = V + NX;
  bf16* P = VT + NX;                   // [B][S][S] bf16
  f16* E = (f16*)(P + (long)B_ * SS);  // [B][S][S] f16
  bf16* attn = Q;                      // attn overwrites dead Q

  dim3 blk(256);
  dim3 blk512(512);

  // fused prep: x->bf16, 4 weight transposes, mask pack (one launch)
  prep<<<dim3(7168), blk, 0, stream>>>(
      x, (const float*)d_in[2], (const float*)d_in[4], (const float*)d_in[6],
      (const float*)d_in[8], masks, xc, WqT, pk);

  // fused Q|K|V projection: [8192,1024] x [1024,3072], 256x128 tiles
  // grid 24x32 = 768 blocks = 1.5 rounds at 2 blocks/CU
  gemmA<bf16, MODE_QKV><<<dim3(24, 32), blk512, 0, stream>>>(
      xc, D_, WqT, 0, D_, Q, D_, bq, bk, bv, 1.0f, D_);

  // VT[b][d][s] = V[b][s][d]
  transposeB<<<dim3(16, 32, B_), blk, 0, stream>>>(V, VT, S_, D_, SD, SD);

  // E = exp(Q K^T / 32) : flat [8192,1024] x K[z][2048,1024], z = row>>11
  // grid 16x32 = 512 blocks = 1 exact round at 2 blocks/CU
  gemmA<f16, MODE_EXP><<<dim3(16, 32), blk512, 0, stream>>>(
      Q, D_, K, SD, D_, E, S_, nullptr, nullptr, nullptr, 1.0f / 32.0f, D_);

  // P = E * sum_m mask_m / rowsum_m / M
  softmax_combine<<<dim3(S_, B_), blk, 0, stream>>>(E, pk, P);

  // attn = P @ V : flat [8192,2048] x VT[z][1024,2048], K=2048
  // grid 8x32 = 256 blocks (spreads 1/CU)
  gemmA<bf16, MODE_PV><<<dim3(8, 32), blk512, 0, stream>>>(
      P, S_, VT, SD, S_, attn, D_, nullptr, nullptr, nullptr, 1.0f, S_);

  // out = attn @ Wo + bo : fp32 epilogue straight to d_out
  gemmA<float, MODE_PLAIN><<<dim3(8, 32), blk512, 0, stream>>>(
      attn, D_, WoT, 0, D_, out, D_, bo, nullptr, nullptr, 1.0f, D_);
}